// Round 8
// baseline (153.465 us; speedup 1.0000x reference)
//
#include <hip/hip_runtime.h>

#define CC 8
#define HH 256
#define WW 512
#define KK 9
#define SEGW 128
#define XROW 136   // 4 left halo + 128 body + 4 right halo

__global__ __launch_bounds__(256) void dynfilter_kernel(
    const float* __restrict__ x,
    const float* __restrict__ filt,
    const float* __restrict__ fbias,
    float* __restrict__ out)
{
    __shared__ __align__(16) float xs[KK][CC][XROW];   // 9*8*136*4 = 39168 B -> 4 blocks/CU

    const int tid = threadIdx.x;
    const int bid = blockIdx.x;          // 2048 = seg(4) * h(256) * n(2)
    const int seg = bid & 3;
    const int h   = (bid >> 2) & 255;
    const int n   = bid >> 10;

    const int pxg = tid & 63;            // 64 groups of 2 px = 128 px
    const int cgr = tid >> 6;            // 4 channel-pairs
    const int c0  = cgr << 1;
    const int w0  = seg * SEGW + (pxg << 1);

    const int lane32 = tid & 31;         // staging: 8 channels x 32 lanes
    const int cstage = tid >> 5;
    const size_t HW = (size_t)HH * WW;
    const float* xc = x + ((size_t)(n * CC + cstage)) * HW;

    // ---- stage ALL 9 x rows (h-4..h+4), zero-padded; the ONLY barrier follows ----
    {
        const int wbody = seg * SEGW + (lane32 << 2);
        const int whalo = (lane32 == 0) ? (seg * SEGW - 4) : (seg * SEGW + SEGW);
        const int ihalo = (lane32 == 0) ? 0 : (XROW - 4);
        for (int r = 0; r < KK; ++r) {
            const int hh = h + r - 4;
            const bool rowok = (unsigned)hh < (unsigned)HH;
            const float* src = xc + (size_t)hh * WW;
            float4 sb = make_float4(0.f, 0.f, 0.f, 0.f);
            float4 sh = sb;
            if (rowok) sb = *(const float4*)(src + wbody);
            if (lane32 < 2 && rowok && (unsigned)whalo < (unsigned)WW)
                sh = *(const float4*)(src + whalo);
            *(float4*)&xs[r][cstage][4 + (lane32 << 2)] = sb;
            if (lane32 < 2) *(float4*)&xs[r][cstage][ihalo] = sh;
        }
    }

    const float* fptr = filt + ((size_t)(n * 81) * HH + h) * WW + w0;

    float a00, a01, a10, a11;
    {
        const float2 fb = *(const float2*)(fbias + ((size_t)(n * HH + h)) * WW + w0);
        a00 = fb.x; a01 = fb.y; a10 = fb.x; a11 = fb.y;
    }

    // prefetch iter-0 filters (they land during the barrier drain anyway)
    float2 f0 = *(const float2*)(fptr + 0 * HW);
    float2 f1 = *(const float2*)(fptr + 1 * HW);
    float2 f2 = *(const float2*)(fptr + 2 * HW);
    float2 f3 = *(const float2*)(fptr + 3 * HW);
    float2 f4 = *(const float2*)(fptr + 4 * HW);
    float2 f5 = *(const float2*)(fptr + 5 * HW);
    float2 f6 = *(const float2*)(fptr + 6 * HW);
    float2 f7 = *(const float2*)(fptr + 7 * HW);
    float2 f8 = *(const float2*)(fptr + 8 * HW);

    __syncthreads();   // single barrier in the whole kernel

    // ---- barrier-free main loop over tap rows, filters software-pipelined ----
    // unroll(disable): auto-unroll would hoist all 81 filter loads -> spill (R3-R5).
    #pragma clang loop unroll(disable)
    for (int i = 0; i < KK; ++i) {
        // prefetch next iteration's filter taps — with no barrier ahead,
        // these genuinely stay in flight under this iteration's compute
        float2 g0, g1, g2, g3, g4, g5, g6, g7, g8;
        g0 = g1 = g2 = g3 = g4 = g5 = g6 = g7 = g8 = make_float2(0.f, 0.f);
        if (i < KK - 1) {
            const float* fi = fptr + (size_t)(i + 1) * KK * HW;
            g0 = *(const float2*)(fi + 0 * HW);
            g1 = *(const float2*)(fi + 1 * HW);
            g2 = *(const float2*)(fi + 2 * HW);
            g3 = *(const float2*)(fi + 3 * HW);
            g4 = *(const float2*)(fi + 4 * HW);
            g5 = *(const float2*)(fi + 5 * HW);
            g6 = *(const float2*)(fi + 6 * HW);
            g7 = *(const float2*)(fi + 7 * HW);
            g8 = *(const float2*)(fi + 8 * HW);
        }

        // channel c0
        {
            const float* xp = &xs[i][c0][pxg << 1];
            float2 v0 = *(const float2*)(xp + 0);
            float2 v1 = *(const float2*)(xp + 2);
            float2 v2 = *(const float2*)(xp + 4);
            float2 v3 = *(const float2*)(xp + 6);
            float2 v4 = *(const float2*)(xp + 8);
            a00 = fmaf(f0.x, v0.x, a00);  a01 = fmaf(f0.y, v0.y, a01);
            a00 = fmaf(f1.x, v0.y, a00);  a01 = fmaf(f1.y, v1.x, a01);
            a00 = fmaf(f2.x, v1.x, a00);  a01 = fmaf(f2.y, v1.y, a01);
            a00 = fmaf(f3.x, v1.y, a00);  a01 = fmaf(f3.y, v2.x, a01);
            a00 = fmaf(f4.x, v2.x, a00);  a01 = fmaf(f4.y, v2.y, a01);
            a00 = fmaf(f5.x, v2.y, a00);  a01 = fmaf(f5.y, v3.x, a01);
            a00 = fmaf(f6.x, v3.x, a00);  a01 = fmaf(f6.y, v3.y, a01);
            a00 = fmaf(f7.x, v3.y, a00);  a01 = fmaf(f7.y, v4.x, a01);
            a00 = fmaf(f8.x, v4.x, a00);  a01 = fmaf(f8.y, v4.y, a01);
        }
        // channel c0+1
        {
            const float* xp = &xs[i][c0 + 1][pxg << 1];
            float2 v0 = *(const float2*)(xp + 0);
            float2 v1 = *(const float2*)(xp + 2);
            float2 v2 = *(const float2*)(xp + 4);
            float2 v3 = *(const float2*)(xp + 6);
            float2 v4 = *(const float2*)(xp + 8);
            a10 = fmaf(f0.x, v0.x, a10);  a11 = fmaf(f0.y, v0.y, a11);
            a10 = fmaf(f1.x, v0.y, a10);  a11 = fmaf(f1.y, v1.x, a11);
            a10 = fmaf(f2.x, v1.x, a10);  a11 = fmaf(f2.y, v1.y, a11);
            a10 = fmaf(f3.x, v1.y, a10);  a11 = fmaf(f3.y, v2.x, a11);
            a10 = fmaf(f4.x, v2.x, a10);  a11 = fmaf(f4.y, v2.y, a11);
            a10 = fmaf(f5.x, v2.y, a10);  a11 = fmaf(f5.y, v3.x, a11);
            a10 = fmaf(f6.x, v3.x, a10);  a11 = fmaf(f6.y, v3.y, a11);
            a10 = fmaf(f7.x, v3.y, a10);  a11 = fmaf(f7.y, v4.x, a11);
            a10 = fmaf(f8.x, v4.x, a10);  a11 = fmaf(f8.y, v4.y, a11);
        }

        f0 = g0; f1 = g1; f2 = g2; f3 = g3; f4 = g4;
        f5 = g5; f6 = g6; f7 = g7; f8 = g8;
    }

    *(float2*)(out + ((size_t)(n * CC + c0) * HH + h) * WW + w0) = make_float2(a00, a01);
    *(float2*)(out + ((size_t)(n * CC + c0 + 1) * HH + h) * WW + w0) = make_float2(a10, a11);
}

extern "C" void kernel_launch(void* const* d_in, const int* in_sizes, int n_in,
                              void* d_out, int out_size, void* d_ws, size_t ws_size,
                              hipStream_t stream) {
    const float* x  = (const float*)d_in[0];
    const float* f  = (const float*)d_in[1];
    const float* fb = (const float*)d_in[2];
    float* o = (float*)d_out;
    hipLaunchKernelGGL(dynfilter_kernel, dim3(2048), dim3(256), 0, stream,
                       x, f, fb, o);
}